// Round 5
// baseline (232.789 us; speedup 1.0000x reference)
//
#include <hip/hip_runtime.h>
#include <stdint.h>

#define HW 16384
#define CH 384
#define NSPLIT 16

typedef float  f32x4  __attribute__((ext_vector_type(4)));
typedef short  short8 __attribute__((ext_vector_type(8)));
typedef __bf16 bf16x8 __attribute__((ext_vector_type(8)));
typedef unsigned short u16;
typedef u16 u16x4 __attribute__((ext_vector_type(4)));

__device__ __forceinline__ u16 f2bf(float f) {
  union { float f; uint32_t u; } v; v.f = f;
  uint32_t r = v.u + 0x7fffu + ((v.u >> 16) & 1u);
  return (u16)(r >> 16);
}

__device__ __forceinline__ f32x4 zero4() { f32x4 z = {0.f, 0.f, 0.f, 0.f}; return z; }

__device__ __forceinline__ f32x4 mfma_bf16(short8 a, short8 b, f32x4 c) {
  return __builtin_amdgcn_mfma_f32_16x16x32_bf16(
      __builtin_bit_cast(bf16x8, a), __builtin_bit_cast(bf16x8, b), c, 0, 0, 0);
}

// async global->LDS, 16B per lane (dest = wave-uniform base + lane*16)
__device__ __forceinline__ void gload16(const void* g, void* lds) {
  auto gp = (const __attribute__((address_space(1))) uint32_t*)(uintptr_t)g;
  auto lp = (__attribute__((address_space(3))) uint32_t*)(uintptr_t)lds;
  __builtin_amdgcn_global_load_lds(gp, lp, 16, 0, 0);
}

// ---- fp32 -> bf16 weight convert --------------------------------------------
__global__ void k_convert_w(const float* __restrict__ w, u16* __restrict__ o) {
  int i = blockIdx.x * 256 + threadIdx.x;
  if (i < 1152 * CH) o[i] = f2bf(w[i]);
}

// ---- x[b][c][n] fp32 -> xT[b][n][c] bf16; 64x64 tile, f32x4 loads, short8 stores
__global__ __launch_bounds__(256) void k_transpose_x(const float* __restrict__ x,
                                                     u16* __restrict__ xT) {
  __shared__ u16 tile[64][72];  // [n][c], row stride 144B -> uniform bank spread
  const int b = blockIdx.z, c0 = blockIdx.y * 64, n0 = blockIdx.x * 64;
  const int t = threadIdx.x;
  const float* xb = x + (size_t)b * CH * HW;
  const int nq = t & 15;   // n-quad within tile
  const int cr = t >> 4;   // 16 c-rows per pass
#pragma unroll
  for (int jj = 0; jj < 4; ++jj) {
    const int c = cr + jj * 16;
    f32x4 v = *(const f32x4*)(xb + (size_t)(c0 + c) * HW + n0 + nq * 4);
#pragma unroll
    for (int i = 0; i < 4; ++i) tile[nq * 4 + i][c] = f2bf(v[i]);
  }
  __syncthreads();
  u16* xtb = xT + (size_t)b * HW * CH;
  const int cc = t & 7;    // 16B chunk in c
  const int r0 = t >> 3;   // 32 rows per pass
#pragma unroll
  for (int jj = 0; jj < 2; ++jj) {
    const int r = r0 + jj * 32;
    short8 v = *(const short8*)(&tile[r][cc * 8]);
    *(short8*)(xtb + (size_t)(n0 + r) * CH + c0 + cc * 8) = v;
  }
}

// ---- GEMM K32 tile staging into paired-row LDS ------------------------------
// Tile = 128 global rows x 32 u16 (8 KB). LDS layout: 64 rows of 128 B; LDS row
// r holds global rows 2r (logical slots 0-3) and 2r+1 (slots 4-7), 16B slots
// XOR-swizzled: physical slot p stores logical slot g8 = p ^ (r & 7). Dest is
// linear (wave base + lane*16, rule 21): thread t -> LDS row t>>3, phys slot
// t&7; the swizzle is applied to the GLOBAL source address.
__device__ __forceinline__ void stage32p(u16* lds, const u16* __restrict__ g, int t) {
  const int w = t >> 6;
#pragma unroll
  for (int s = 0; s < 2; ++s) {
    const int r = s * 32 + (t >> 3);
    const int g8 = (t & 7) ^ (r & 7);
    const int gr = 2 * r + (g8 >> 2);
    gload16(g + (size_t)gr * CH + (g8 & 3) * 8, lds + s * 2048 + w * 512);
  }
}

// MODE 0: A=qkv_w_bf16[1152][384], B=xT, out: q,k -> qk[b][o][n] (bf16, in d_out),
//         v -> vT[b][n][o-768] (bf16, ws).  MODE 1: A=M[b][384][384], out fp32.
// Ring-4 buffers, stage-ahead-3, ONE barrier + counted vmcnt per K-step,
// no lgkmcnt drains (WAR separated by ring distance, see race analysis).
template <int MODE>
__global__ __launch_bounds__(256) void k_gemm(const u16* __restrict__ Aw,
                                              const u16* __restrict__ Bx,
                                              u16* __restrict__ qk,
                                              u16* __restrict__ vT,
                                              float* __restrict__ outp) {
  __shared__ u16 Ws[4][64 * 64];
  __shared__ u16 Xs[4][64 * 64];
  const int b = blockIdx.z, ot = blockIdx.y, nt = blockIdx.x;
  const int t = threadIdx.x, lane = t & 63, w = t >> 6;
  const int wo = w & 1, wn = w >> 1;
  const u16* Ab = (MODE == 0 ? Aw : Aw + (size_t)b * CH * CH) + (size_t)ot * 128 * CH;
  const u16* Bb = Bx + (size_t)b * HW * CH + (size_t)nt * 128 * CH;
  const bool swp = (MODE == 0) && (ot >= 6);  // v tiles: swap operands for vT stores

  f32x4 acc[4][4];
#pragma unroll
  for (int i = 0; i < 4; ++i)
#pragma unroll
    for (int j = 0; j < 4; ++j) acc[i][j] = zero4();

  // prologue: tiles 0,1,2 in flight (4 loads/thread each: 2 W + 2 X)
#pragma unroll
  for (int p = 0; p < 3; ++p) {
    stage32p(Ws[p], Ab + p * 32, t);
    stage32p(Xs[p], Bb + p * 32, t);
  }

  const int ks = lane >> 4;  // 8-u16 k-chunk 0..3 within the 32-k tile

  for (int kt = 0; kt < 12; ++kt) {
    // retire tile kt's 4 loads (FIFO); keep kt+1,kt+2(,kt+3) in flight
    if (kt <= 9)       asm volatile("s_waitcnt vmcnt(8)" ::: "memory");
    else if (kt == 10) asm volatile("s_waitcnt vmcnt(4)" ::: "memory");
    else               asm volatile("s_waitcnt vmcnt(0)" ::: "memory");
    asm volatile("s_barrier" ::: "memory");  // all waves' tile-kt loads visible
    if (kt < 9) {  // stage tile kt+3 into buf[(kt+3)&3] (readers done at kt-1)
      stage32p(Ws[(kt + 3) & 3], Ab + (kt + 3) * 32, t);
      stage32p(Xs[(kt + 3) & 3], Bb + (kt + 3) * 32, t);
    }
    const u16* Wc = Ws[kt & 3];
    const u16* Xc = Xs[kt & 3];
    short8 af[4], bfr[4];
#pragma unroll
    for (int mi = 0; mi < 4; ++mi) {
      const int gr = wo * 64 + mi * 16 + (lane & 15);
      const int r = gr >> 1;
      const int p = ((gr & 1) * 4 + ks) ^ (r & 7);
      af[mi] = *(const short8*)(Wc + r * 64 + p * 8);
    }
#pragma unroll
    for (int ni = 0; ni < 4; ++ni) {
      const int gr = wn * 64 + ni * 16 + (lane & 15);
      const int r = gr >> 1;
      const int p = ((gr & 1) * 4 + ks) ^ (r & 7);
      bfr[ni] = *(const short8*)(Xc + r * 64 + p * 8);
    }
    if (!swp) {
#pragma unroll
      for (int ni = 0; ni < 4; ++ni)
#pragma unroll
        for (int mi = 0; mi < 4; ++mi)
          acc[ni][mi] = mfma_bf16(bfr[ni], af[mi], acc[ni][mi]);  // rows=n, cols=o
    } else {
#pragma unroll
      for (int ni = 0; ni < 4; ++ni)
#pragma unroll
        for (int mi = 0; mi < 4; ++mi)
          acc[ni][mi] = mfma_bf16(af[mi], bfr[ni], acc[ni][mi]);  // rows=o, cols=n
    }
  }

  if (MODE == 1) {
    float* ob = outp + (size_t)b * CH * HW;
#pragma unroll
    for (int ni = 0; ni < 4; ++ni)
#pragma unroll
      for (int mi = 0; mi < 4; ++mi) {
        int o = ot * 128 + wo * 64 + mi * 16 + (lane & 15);
        int n = nt * 128 + wn * 64 + ni * 16 + ((lane >> 4) << 2);
        *(f32x4*)(ob + (size_t)o * HW + n) = acc[ni][mi];
      }
  } else if (!swp) {
    u16* qb = qk + (size_t)b * 768 * HW;
#pragma unroll
    for (int ni = 0; ni < 4; ++ni)
#pragma unroll
      for (int mi = 0; mi < 4; ++mi) {
        int o = ot * 128 + wo * 64 + mi * 16 + (lane & 15);
        int n = nt * 128 + wn * 64 + ni * 16 + ((lane >> 4) << 2);
        u16x4 p;
#pragma unroll
        for (int j = 0; j < 4; ++j) p[j] = f2bf(acc[ni][mi][j]);
        *(u16x4*)(qb + (size_t)o * HW + n) = p;
      }
  } else {
    u16* vb = vT + (size_t)b * HW * CH;
#pragma unroll
    for (int ni = 0; ni < 4; ++ni)
#pragma unroll
      for (int mi = 0; mi < 4; ++mi) {
        int o = (ot - 6) * 128 + wo * 64 + mi * 16 + ((lane >> 4) << 2);
        int n = nt * 128 + wn * 64 + ni * 16 + (lane & 15);
        u16x4 p;
#pragma unroll
        for (int j = 0; j < 4; ++j) p[j] = f2bf(acc[ni][mi][j]);
        *(u16x4*)(vb + (size_t)n * CH + o) = p;
      }
  }
}

// ---- Gram: per (b,h,split): S[48][48] += q.k^T over n-chunk; norms via diag(q.q^T)
__global__ __launch_bounds__(256) void k_gram(const u16* __restrict__ qk,
                                              float* __restrict__ part) {
  const int s = blockIdx.x, h = blockIdx.y, b = blockIdx.z;
  const int t = threadIdx.x, lane = t & 63, w = t >> 6;
  const u16* qb = qk + ((size_t)b * 768 + h * 48) * HW;
  const u16* kb = qb + (size_t)CH * HW;
  const int n0 = s * 1024 + w * 256;

  f32x4 S[3][3], Q[3], K2[3];
#pragma unroll
  for (int m = 0; m < 3; ++m) {
    Q[m] = zero4(); K2[m] = zero4();
#pragma unroll
    for (int d = 0; d < 3; ++d) S[m][d] = zero4();
  }
  for (int st = 0; st < 8; ++st) {
    const int n = n0 + st * 32 + ((lane >> 4) << 3);
    short8 qf[3], kf[3];
#pragma unroll
    for (int m = 0; m < 3; ++m)
      qf[m] = *(const short8*)(qb + (size_t)(m * 16 + (lane & 15)) * HW + n);
#pragma unroll
    for (int d = 0; d < 3; ++d)
      kf[d] = *(const short8*)(kb + (size_t)(d * 16 + (lane & 15)) * HW + n);
#pragma unroll
    for (int m = 0; m < 3; ++m) {
      Q[m] = mfma_bf16(qf[m], qf[m], Q[m]);
      K2[m] = mfma_bf16(kf[m], kf[m], K2[m]);
#pragma unroll
      for (int d = 0; d < 3; ++d) S[m][d] = mfma_bf16(qf[m], kf[d], S[m][d]);
    }
  }
  __shared__ float Sw[4][2304];
  __shared__ float Nw[4][96];
#pragma unroll
  for (int m = 0; m < 3; ++m)
#pragma unroll
    for (int d = 0; d < 3; ++d)
#pragma unroll
      for (int j = 0; j < 4; ++j)
        Sw[w][(m * 16 + ((lane >> 4) << 2) + j) * 48 + d * 16 + (lane & 15)] = S[m][d][j];
#pragma unroll
  for (int m = 0; m < 3; ++m)
#pragma unroll
    for (int j = 0; j < 4; ++j)
      if ((((lane >> 4) << 2) + j) == (lane & 15)) {
        Nw[w][m * 16 + (lane & 15)] = Q[m][j];
        Nw[w][48 + m * 16 + (lane & 15)] = K2[m][j];
      }
  __syncthreads();
  float* dst = part + (size_t)((b * 8 + h) * NSPLIT + s) * 2400;
  for (int idx = t; idx < 2304; idx += 256)
    dst[idx] = Sw[0][idx] + Sw[1][idx] + Sw[2][idx] + Sw[3][idx];
  if (t < 96) dst[2304 + t] = Nw[0][t] + Nw[1][t] + Nw[2][t] + Nw[3][t];
}

// ---- softmax + M = proj_w(block) @ attn  (per b,h) --------------------------
__global__ __launch_bounds__(384) void k_softmax_M(const float* __restrict__ part,
                                                   const float* __restrict__ projw,
                                                   const float* __restrict__ temp,
                                                   u16* __restrict__ Mbf) {
  const int h = blockIdx.x, b = blockIdx.y;
  const int t = threadIdx.x;
  __shared__ float S[2304];
  __shared__ float attn[48][48];
  __shared__ float nrm[96];
  const float* p = part + (size_t)(b * 8 + h) * NSPLIT * 2400;
  for (int idx = t; idx < 2304; idx += 384) {
    float a = 0.f;
#pragma unroll
    for (int s = 0; s < NSPLIT; ++s) a += p[(size_t)s * 2400 + idx];
    S[idx] = a;
  }
  if (t < 96) {
    float a = 0.f;
#pragma unroll
    for (int s = 0; s < NSPLIT; ++s) a += p[(size_t)s * 2400 + 2304 + t];
    nrm[t] = a;
  }
  __syncthreads();
  if (t < 48) {
    const float th = temp[h];
    const float inq = 1.f / fmaxf(sqrtf(nrm[t]), 1e-12f);
    float l[48];
    float mx = -3.4e38f;
#pragma unroll
    for (int d = 0; d < 48; ++d) {
      float ik = 1.f / fmaxf(sqrtf(nrm[48 + d]), 1e-12f);
      float lg = S[t * 48 + d] * inq * ik * th;
      l[d] = lg;
      mx = fmaxf(mx, lg);
    }
    float sum = 0.f;
#pragma unroll
    for (int d = 0; d < 48; ++d) { float e = __expf(l[d] - mx); l[d] = e; sum += e; }
    float inv = 1.f / sum;
#pragma unroll
    for (int d = 0; d < 48; ++d) attn[t][d] = l[d] * inv;
  }
  __syncthreads();
  const int o = t;
  float pw[48];
#pragma unroll
  for (int c = 0; c < 48; ++c) pw[c] = projw[(size_t)o * CH + h * 48 + c];
  u16* Mb = Mbf + ((size_t)b * CH + o) * CH + h * 48;
#pragma unroll 4
  for (int d = 0; d < 48; ++d) {
    float a = 0.f;
#pragma unroll
    for (int c = 0; c < 48; ++c) a = fmaf(pw[c], attn[c][d], a);
    Mb[d] = f2bf(a);
  }
}

extern "C" void kernel_launch(void* const* d_in, const int* in_sizes, int n_in,
                              void* d_out, int out_size, void* d_ws, size_t ws_size,
                              hipStream_t stream) {
  const float* x     = (const float*)d_in[0];
  const float* qkvw  = (const float*)d_in[1];
  const float* projw = (const float*)d_in[2];
  const float* temp  = (const float*)d_in[3];
  float* out = (float*)d_out;
  char* ws = (char*)d_ws;

  // ws layout (bytes)
  u16*   xT   = (u16*)(ws);                      // 4*16384*384*2 = 50331648
  u16*   vT   = (u16*)(ws + 50331648);           // 50331648
  u16*   wbf  = (u16*)(ws + 100663296);          // 1152*384*2 = 884736
  u16*   Mbf  = (u16*)(ws + 101548032);          // 4*384*384*2 = 1179648
  float* part = (float*)(ws + 102727680);        // 512*2400*4 = 4915200
  u16*   qkbuf = (u16*)d_out;                    // q,k bf16 live in d_out until GEMM2

  k_convert_w<<<dim3((1152 * CH + 255) / 256), 256, 0, stream>>>(qkvw, wbf);
  k_transpose_x<<<dim3(HW / 64, CH / 64, 4), 256, 0, stream>>>(x, xT);
  k_gemm<0><<<dim3(128, 9, 4), 256, 0, stream>>>(wbf, xT, qkbuf, vT, nullptr);
  k_gram<<<dim3(NSPLIT, 8, 4), 256, 0, stream>>>(qkbuf, part);
  k_softmax_M<<<dim3(8, 4), 384, 0, stream>>>(part, projw, temp, Mbf);
  k_gemm<1><<<dim3(128, 3, 4), 256, 0, stream>>>(Mbf, vT, nullptr, nullptr, out);
}

// Round 6
// 225.132 us; speedup vs baseline: 1.0340x; 1.0340x over previous
//
#include <hip/hip_runtime.h>
#include <stdint.h>

#define HW 16384
#define CH 384
#define NSPLIT 16

typedef float  f32x4  __attribute__((ext_vector_type(4)));
typedef short  short8 __attribute__((ext_vector_type(8)));
typedef __bf16 bf16x8 __attribute__((ext_vector_type(8)));
typedef unsigned short u16;
typedef u16 u16x4 __attribute__((ext_vector_type(4)));

__device__ __forceinline__ u16 f2bf(float f) {
  union { float f; uint32_t u; } v; v.f = f;
  uint32_t r = v.u + 0x7fffu + ((v.u >> 16) & 1u);
  return (u16)(r >> 16);
}

__device__ __forceinline__ f32x4 zero4() { f32x4 z = {0.f, 0.f, 0.f, 0.f}; return z; }

__device__ __forceinline__ f32x4 mfma_bf16(short8 a, short8 b, f32x4 c) {
  return __builtin_amdgcn_mfma_f32_16x16x32_bf16(
      __builtin_bit_cast(bf16x8, a), __builtin_bit_cast(bf16x8, b), c, 0, 0, 0);
}

// async global->LDS, 16B per lane (dest = wave-uniform base + lane*16)
__device__ __forceinline__ void gload16(const void* g, void* lds) {
  auto gp = (const __attribute__((address_space(1))) uint32_t*)(uintptr_t)g;
  auto lp = (__attribute__((address_space(3))) uint32_t*)(uintptr_t)lds;
  __builtin_amdgcn_global_load_lds(gp, lp, 16, 0, 0);
}

// ---- fp32 -> bf16 weight convert --------------------------------------------
__global__ void k_convert_w(const float* __restrict__ w, u16* __restrict__ o) {
  int i = blockIdx.x * 256 + threadIdx.x;
  if (i < 1152 * CH) o[i] = f2bf(w[i]);
}

// ---- x[b][c][n] fp32 -> xT[b][n][c] bf16; 64x64 tile, f32x4 loads, short8 stores
__global__ __launch_bounds__(256) void k_transpose_x(const float* __restrict__ x,
                                                     u16* __restrict__ xT) {
  __shared__ u16 tile[64][72];  // [n][c], row stride 144B -> uniform bank spread
  const int b = blockIdx.z, c0 = blockIdx.y * 64, n0 = blockIdx.x * 64;
  const int t = threadIdx.x;
  const float* xb = x + (size_t)b * CH * HW;
  const int nq = t & 15;   // n-quad within tile
  const int cr = t >> 4;   // 16 c-rows per pass
#pragma unroll
  for (int jj = 0; jj < 4; ++jj) {
    const int c = cr + jj * 16;
    f32x4 v = *(const f32x4*)(xb + (size_t)(c0 + c) * HW + n0 + nq * 4);
#pragma unroll
    for (int i = 0; i < 4; ++i) tile[nq * 4 + i][c] = f2bf(v[i]);
  }
  __syncthreads();
  u16* xtb = xT + (size_t)b * HW * CH;
  const int cc = t & 7;    // 16B chunk in c
  const int r0 = t >> 3;   // 32 rows per pass
#pragma unroll
  for (int jj = 0; jj < 2; ++jj) {
    const int r = r0 + jj * 32;
    short8 v = *(const short8*)(&tile[r][cc * 8]);
    *(short8*)(xtb + (size_t)(n0 + r) * CH + c0 + cc * 8) = v;
  }
}

// ---- GEMM K32 tile staging into paired-row LDS ------------------------------
// Tile = 128 global rows x 32 u16 (8 KB). LDS layout: 64 rows of 128 B; LDS row
// r holds global rows 2r (logical slots 0-3) and 2r+1 (slots 4-7), 16B slots
// XOR-swizzled: physical slot p stores logical slot g8 = p ^ (r & 7). Dest is
// linear (wave base + lane*16, rule 21): thread t -> LDS row t>>3, phys slot
// t&7; the swizzle is applied to the GLOBAL source address.
__device__ __forceinline__ void stage32p(u16* lds, const u16* __restrict__ g, int t) {
  const int w = t >> 6;
#pragma unroll
  for (int s = 0; s < 2; ++s) {
    const int r = s * 32 + (t >> 3);
    const int g8 = (t & 7) ^ (r & 7);
    const int gr = 2 * r + (g8 >> 2);
    gload16(g + (size_t)gr * CH + (g8 & 3) * 8, lds + s * 2048 + w * 512);
  }
}

// MODE 0: A=qkv_w_bf16[1152][384], B=xT, out: q,k -> qk[b][o][n] (bf16, in d_out),
//         v -> vT[b][n][o-768] (bf16, ws).  MODE 1: A=M[b][384][384], out fp32.
// Ring-4 buffers, stage-ahead-3, ONE barrier + counted vmcnt per K-step.
// Grid flattened; bijective XCD-chunk swizzle with ot FASTEST inside each
// XCD's chunk, so the NOT blocks sharing one B-panel run back-to-back on the
// same XCD -> B staged from that XCD's L2 instead of L3 (m204 pattern).
template <int MODE>
__global__ __launch_bounds__(256) void k_gemm(const u16* __restrict__ Aw,
                                              const u16* __restrict__ Bx,
                                              u16* __restrict__ qk,
                                              u16* __restrict__ vT,
                                              float* __restrict__ outp) {
  constexpr int NOT = (MODE == 0) ? 9 : 3;      // output-row tiles (of 128)
  constexpr int NWG = NOT * 128 * 4;            // total workgroups
  constexpr int CHUNK = NWG / 8;                // per-XCD contiguous chunk
  const int orig = blockIdx.x;
  const int L = (orig & 7) * CHUNK + (orig >> 3);  // bijective (NWG % 8 == 0)
  const int ot = L % NOT;
  const int ntg = L / NOT;
  const int b = ntg >> 7;
  const int nt = ntg & 127;

  __shared__ u16 Ws[4][64 * 64];
  __shared__ u16 Xs[4][64 * 64];
  const int t = threadIdx.x, lane = t & 63, w = t >> 6;
  const int wo = w & 1, wn = w >> 1;
  const u16* Ab = (MODE == 0 ? Aw : Aw + (size_t)b * CH * CH) + (size_t)ot * 128 * CH;
  const u16* Bb = Bx + (size_t)b * HW * CH + (size_t)nt * 128 * CH;
  const bool swp = (MODE == 0) && (ot >= 6);  // v tiles: swap operands for vT stores

  f32x4 acc[4][4];
#pragma unroll
  for (int i = 0; i < 4; ++i)
#pragma unroll
    for (int j = 0; j < 4; ++j) acc[i][j] = zero4();

  // prologue: tiles 0,1,2 in flight (4 loads/thread each: 2 W + 2 X)
#pragma unroll
  for (int p = 0; p < 3; ++p) {
    stage32p(Ws[p], Ab + p * 32, t);
    stage32p(Xs[p], Bb + p * 32, t);
  }

  const int ks = lane >> 4;  // 8-u16 k-chunk 0..3 within the 32-k tile

  for (int kt = 0; kt < 12; ++kt) {
    // retire tile kt's 4 loads (FIFO); keep kt+1,kt+2(,kt+3) in flight
    if (kt <= 9)       asm volatile("s_waitcnt vmcnt(8)" ::: "memory");
    else if (kt == 10) asm volatile("s_waitcnt vmcnt(4)" ::: "memory");
    else               asm volatile("s_waitcnt vmcnt(0)" ::: "memory");
    asm volatile("s_barrier" ::: "memory");  // all waves' tile-kt loads visible
    if (kt < 9) {  // stage tile kt+3 into buf[(kt+3)&3] (readers done at kt-1)
      stage32p(Ws[(kt + 3) & 3], Ab + (kt + 3) * 32, t);
      stage32p(Xs[(kt + 3) & 3], Bb + (kt + 3) * 32, t);
    }
    const u16* Wc = Ws[kt & 3];
    const u16* Xc = Xs[kt & 3];
    short8 af[4], bfr[4];
#pragma unroll
    for (int mi = 0; mi < 4; ++mi) {
      const int gr = wo * 64 + mi * 16 + (lane & 15);
      const int r = gr >> 1;
      const int p = ((gr & 1) * 4 + ks) ^ (r & 7);
      af[mi] = *(const short8*)(Wc + r * 64 + p * 8);
    }
#pragma unroll
    for (int ni = 0; ni < 4; ++ni) {
      const int gr = wn * 64 + ni * 16 + (lane & 15);
      const int r = gr >> 1;
      const int p = ((gr & 1) * 4 + ks) ^ (r & 7);
      bfr[ni] = *(const short8*)(Xc + r * 64 + p * 8);
    }
    if (!swp) {
#pragma unroll
      for (int ni = 0; ni < 4; ++ni)
#pragma unroll
        for (int mi = 0; mi < 4; ++mi)
          acc[ni][mi] = mfma_bf16(bfr[ni], af[mi], acc[ni][mi]);  // rows=n, cols=o
    } else {
#pragma unroll
      for (int ni = 0; ni < 4; ++ni)
#pragma unroll
        for (int mi = 0; mi < 4; ++mi)
          acc[ni][mi] = mfma_bf16(af[mi], bfr[ni], acc[ni][mi]);  // rows=o, cols=n
    }
  }

  if (MODE == 1) {
    float* ob = outp + (size_t)b * CH * HW;
#pragma unroll
    for (int ni = 0; ni < 4; ++ni)
#pragma unroll
      for (int mi = 0; mi < 4; ++mi) {
        int o = ot * 128 + wo * 64 + mi * 16 + (lane & 15);
        int n = nt * 128 + wn * 64 + ni * 16 + ((lane >> 4) << 2);
        *(f32x4*)(ob + (size_t)o * HW + n) = acc[ni][mi];
      }
  } else if (!swp) {
    u16* qb = qk + (size_t)b * 768 * HW;
#pragma unroll
    for (int ni = 0; ni < 4; ++ni)
#pragma unroll
      for (int mi = 0; mi < 4; ++mi) {
        int o = ot * 128 + wo * 64 + mi * 16 + (lane & 15);
        int n = nt * 128 + wn * 64 + ni * 16 + ((lane >> 4) << 2);
        u16x4 p;
#pragma unroll
        for (int j = 0; j < 4; ++j) p[j] = f2bf(acc[ni][mi][j]);
        *(u16x4*)(qb + (size_t)o * HW + n) = p;
      }
  } else {
    u16* vb = vT + (size_t)b * HW * CH;
#pragma unroll
    for (int ni = 0; ni < 4; ++ni)
#pragma unroll
      for (int mi = 0; mi < 4; ++mi) {
        int o = (ot - 6) * 128 + wo * 64 + mi * 16 + ((lane >> 4) << 2);
        int n = nt * 128 + wn * 64 + ni * 16 + (lane & 15);
        u16x4 p;
#pragma unroll
        for (int j = 0; j < 4; ++j) p[j] = f2bf(acc[ni][mi][j]);
        *(u16x4*)(vb + (size_t)n * CH + o) = p;
      }
  }
}

// ---- Gram: per (b,h,split): S[48][48] += q.k^T over n-chunk; norms via diag(q.q^T)
__global__ __launch_bounds__(256) void k_gram(const u16* __restrict__ qk,
                                              float* __restrict__ part) {
  const int s = blockIdx.x, h = blockIdx.y, b = blockIdx.z;
  const int t = threadIdx.x, lane = t & 63, w = t >> 6;
  const u16* qb = qk + ((size_t)b * 768 + h * 48) * HW;
  const u16* kb = qb + (size_t)CH * HW;
  const int n0 = s * 1024 + w * 256;

  f32x4 S[3][3], Q[3], K2[3];
#pragma unroll
  for (int m = 0; m < 3; ++m) {
    Q[m] = zero4(); K2[m] = zero4();
#pragma unroll
    for (int d = 0; d < 3; ++d) S[m][d] = zero4();
  }
  for (int st = 0; st < 8; ++st) {
    const int n = n0 + st * 32 + ((lane >> 4) << 3);
    short8 qf[3], kf[3];
#pragma unroll
    for (int m = 0; m < 3; ++m)
      qf[m] = *(const short8*)(qb + (size_t)(m * 16 + (lane & 15)) * HW + n);
#pragma unroll
    for (int d = 0; d < 3; ++d)
      kf[d] = *(const short8*)(kb + (size_t)(d * 16 + (lane & 15)) * HW + n);
#pragma unroll
    for (int m = 0; m < 3; ++m) {
      Q[m] = mfma_bf16(qf[m], qf[m], Q[m]);
      K2[m] = mfma_bf16(kf[m], kf[m], K2[m]);
#pragma unroll
      for (int d = 0; d < 3; ++d) S[m][d] = mfma_bf16(qf[m], kf[d], S[m][d]);
    }
  }
  __shared__ float Sw[4][2304];
  __shared__ float Nw[4][96];
#pragma unroll
  for (int m = 0; m < 3; ++m)
#pragma unroll
    for (int d = 0; d < 3; ++d)
#pragma unroll
      for (int j = 0; j < 4; ++j)
        Sw[w][(m * 16 + ((lane >> 4) << 2) + j) * 48 + d * 16 + (lane & 15)] = S[m][d][j];
#pragma unroll
  for (int m = 0; m < 3; ++m)
#pragma unroll
    for (int j = 0; j < 4; ++j)
      if ((((lane >> 4) << 2) + j) == (lane & 15)) {
        Nw[w][m * 16 + (lane & 15)] = Q[m][j];
        Nw[w][48 + m * 16 + (lane & 15)] = K2[m][j];
      }
  __syncthreads();
  float* dst = part + (size_t)((b * 8 + h) * NSPLIT + s) * 2400;
  for (int idx = t; idx < 2304; idx += 256)
    dst[idx] = Sw[0][idx] + Sw[1][idx] + Sw[2][idx] + Sw[3][idx];
  if (t < 96) dst[2304 + t] = Nw[0][t] + Nw[1][t] + Nw[2][t] + Nw[3][t];
}

// ---- softmax + M = proj_w(block) @ attn  (per b,h) --------------------------
__global__ __launch_bounds__(384) void k_softmax_M(const float* __restrict__ part,
                                                   const float* __restrict__ projw,
                                                   const float* __restrict__ temp,
                                                   u16* __restrict__ Mbf) {
  const int h = blockIdx.x, b = blockIdx.y;
  const int t = threadIdx.x;
  __shared__ float S[2304];
  __shared__ float attn[48][48];
  __shared__ float nrm[96];
  const float* p = part + (size_t)(b * 8 + h) * NSPLIT * 2400;
  for (int idx = t; idx < 2304; idx += 384) {
    float a = 0.f;
#pragma unroll
    for (int s = 0; s < NSPLIT; ++s) a += p[(size_t)s * 2400 + idx];
    S[idx] = a;
  }
  if (t < 96) {
    float a = 0.f;
#pragma unroll
    for (int s = 0; s < NSPLIT; ++s) a += p[(size_t)s * 2400 + 2304 + t];
    nrm[t] = a;
  }
  __syncthreads();
  if (t < 48) {
    const float th = temp[h];
    const float inq = 1.f / fmaxf(sqrtf(nrm[t]), 1e-12f);
    float l[48];
    float mx = -3.4e38f;
#pragma unroll
    for (int d = 0; d < 48; ++d) {
      float ik = 1.f / fmaxf(sqrtf(nrm[48 + d]), 1e-12f);
      float lg = S[t * 48 + d] * inq * ik * th;
      l[d] = lg;
      mx = fmaxf(mx, lg);
    }
    float sum = 0.f;
#pragma unroll
    for (int d = 0; d < 48; ++d) { float e = __expf(l[d] - mx); l[d] = e; sum += e; }
    float inv = 1.f / sum;
#pragma unroll
    for (int d = 0; d < 48; ++d) attn[t][d] = l[d] * inv;
  }
  __syncthreads();
  const int o = t;
  float pw[48];
#pragma unroll
  for (int c = 0; c < 48; ++c) pw[c] = projw[(size_t)o * CH + h * 48 + c];
  u16* Mb = Mbf + ((size_t)b * CH + o) * CH + h * 48;
#pragma unroll 4
  for (int d = 0; d < 48; ++d) {
    float a = 0.f;
#pragma unroll
    for (int c = 0; c < 48; ++c) a = fmaf(pw[c], attn[c][d], a);
    Mb[d] = f2bf(a);
  }
}

extern "C" void kernel_launch(void* const* d_in, const int* in_sizes, int n_in,
                              void* d_out, int out_size, void* d_ws, size_t ws_size,
                              hipStream_t stream) {
  const float* x     = (const float*)d_in[0];
  const float* qkvw  = (const float*)d_in[1];
  const float* projw = (const float*)d_in[2];
  const float* temp  = (const float*)d_in[3];
  float* out = (float*)d_out;
  char* ws = (char*)d_ws;

  // ws layout (bytes)
  u16*   xT   = (u16*)(ws);                      // 4*16384*384*2 = 50331648
  u16*   vT   = (u16*)(ws + 50331648);           // 50331648
  u16*   wbf  = (u16*)(ws + 100663296);          // 1152*384*2 = 884736
  u16*   Mbf  = (u16*)(ws + 101548032);          // 4*384*384*2 = 1179648
  float* part = (float*)(ws + 102727680);        // 512*2400*4 = 4915200
  u16*   qkbuf = (u16*)d_out;                    // q,k bf16 live in d_out until GEMM2

  k_convert_w<<<dim3((1152 * CH + 255) / 256), 256, 0, stream>>>(qkvw, wbf);
  k_transpose_x<<<dim3(HW / 64, CH / 64, 4), 256, 0, stream>>>(x, xT);
  k_gemm<0><<<dim3(9 * 128 * 4), 256, 0, stream>>>(wbf, xT, qkbuf, vT, nullptr);
  k_gram<<<dim3(NSPLIT, 8, 4), 256, 0, stream>>>(qkbuf, part);
  k_softmax_M<<<dim3(8, 4), 384, 0, stream>>>(part, projw, temp, Mbf);
  k_gemm<1><<<dim3(3 * 128 * 4), 256, 0, stream>>>(Mbf, vT, nullptr, nullptr, out);
}